// Round 7
// baseline (185.699 us; speedup 1.0000x reference)
//
#include <hip/hip_runtime.h>
#include <stdint.h>

#define IN_C 256
#define OUT_C 256
#define HH 56
#define WW 56
#define NB 32
#define HP 58
#define WP 58

#define BMP 112          // pixels per block = 2 output rows
#define NTILE 896        // 32 images * 28 row-pairs
#define XCH 928          // chunks per slab: 4 rows * 58 cols * 4 chunks
#define SLAB_B 14848     // bytes per X slab (4*58*64 i8)

typedef __attribute__((ext_vector_type(4))) int int4v;

typedef const __attribute__((address_space(1))) unsigned int guint_t;
typedef __attribute__((address_space(3))) unsigned int luint_t;

__device__ __forceinline__ void gload16(void* lds, const void* g) {
    __builtin_amdgcn_global_load_lds((guint_t*)g, (luint_t*)lds, 16, 0, 0);
}

// quantize: x -> round(clamp(x*127/5)) as a byte
__device__ __forceinline__ int q8(float f) {
    float c = fminf(fmaxf(f * 25.4f, -127.f), 127.f);
    return __float2int_rn(c) & 255;
}

// ---------------- pre-pass 1: NCHW f32 -> padded NHWC int8 ----------------
__global__ __launch_bounds__(256) void pad_nhwc(const float* __restrict__ x,
                                                unsigned char* __restrict__ xpad) {
    __shared__ float lds[WW * 257];
    int bid = blockIdx.x;
    int n = bid / HP, h = bid % HP;
    unsigned char* dstRow = xpad + (size_t)(n * HP + h) * WP * IN_C;
    bool hin = (h >= 1 && h <= HH);
    if (hin) {
        const float* src = x + (size_t)n * IN_C * (HH * WW) + (h - 1) * WW;
        for (int e = threadIdx.x; e < IN_C * WW; e += 256) {
            int ic = e / WW, w = e - ic * WW;
            lds[w * 257 + ic] = src[(size_t)ic * (HH * WW) + w];
        }
    }
    __syncthreads();
    for (int e = threadIdx.x; e < WP * (IN_C / 16); e += 256) {   // 928
        int wo = e >> 4;
        int icc = e & 15;
        int4v v = {0, 0, 0, 0};
        if (hin && wo >= 1 && wo <= WW) {
            const float* p = &lds[(wo - 1) * 257 + icc * 16];
#pragma unroll
            for (int wi = 0; wi < 4; ++wi) {
                int word = 0;
#pragma unroll
                for (int j = 0; j < 4; ++j) word |= q8(p[wi * 4 + j]) << (8 * j);
                v[wi] = word;
            }
        }
        *(int4v*)(dstRow + wo * IN_C + icc * 16) = v;
    }
}

// ---------- pre-pass 2: OIHW f32 -> A-frag-ready i8 wfr[q][tap][wm][af][lane][16] ----------
// lane chunk: oc = wm*64+af*16+(lane&15), ic = q*64 + (lane>>4)*16 + j  (j = byte)
__global__ __launch_bounds__(256) void wconv(const float* __restrict__ w,
                                             unsigned char* __restrict__ wfr) {
    int i = blockIdx.x * 256 + threadIdx.x;   // 36864 chunks
    int lane = i & 63;
    int af = (i >> 6) & 3;
    int wm = (i >> 8) & 3;
    int qt = i >> 10;                          // 0..35
    int tap = qt % 9;
    int q = qt / 9;
    int oc = wm * 64 + af * 16 + (lane & 15);
    int icb = q * 64 + (lane >> 4) * 16;
    int4v v;
#pragma unroll
    for (int wi = 0; wi < 4; ++wi) {
        int word = 0;
#pragma unroll
        for (int j = 0; j < 4; ++j) {
            int ic = icb + wi * 4 + j;
            word |= (__float2int_rn(w[(size_t)oc * 2304 + ic * 9 + tap]) & 255) << (8 * j);
        }
        v[wi] = word;
    }
    *(int4v*)(wfr + (size_t)i * 16) = v;
}

// ---------------- main: i8 implicit-GEMM, 4 waves, X slab dbuf, reg-pipelined ----------------
__global__ __launch_bounds__(256, 2) void conv_i8(const unsigned char* __restrict__ xpad,
                                                  const unsigned char* __restrict__ wfr,
                                                  float* __restrict__ out) {
    __shared__ unsigned char Xl[2][SLAB_B];

    const int tid = threadIdx.x;
    const int lane = tid & 63;
    const int wm = tid >> 6;                 // 0..3 : 64-oc slice

    const int bid = blockIdx.x;
    const int g = bid >> 3, xq = bid & 7;    // same-image blocks land on same XCD
    const int n = xq * 4 + g / 28;
    const int rg = g % 28;
    const int oh0 = rg * 2;                  // padded rows oh0..oh0+3
    const int pix0 = rg * BMP;

    const unsigned char* xpn = xpad + (size_t)n * HP * WP * IN_C;

    // X staging: physical chunk ci -> (cell = ci>>2, pc = ci&3); logical k-chunk
    // lc = pc ^ f(cell), f(c) = (c ^ (c>>2)) & 3  (rule #21: linear LDS dest +
    // inverse-swizzled source; read applies same f)
    int xgo[4];
#pragma unroll
    for (int k = 0; k < 4; ++k) {
        int ci = tid + k * 256; if (ci > XCH - 1) ci = XCH - 1;
        int cell = ci >> 2, pc = ci & 3;
        int row = cell / 58, col = cell - row * 58;
        int lc = (pc ^ cell ^ (cell >> 2)) & 3;
        xgo[k] = ((oh0 + row) * WP + col) * IN_C + lc * 16;
    }

    const int rlo = lane & 15;
    const int kq = lane >> 4;
    int cellb[7];
#pragma unroll
    for (int xf = 0; xf < 7; ++xf) {
        int pl = xf * 16 + rlo;              // 0..111
        int ohr = (pl >= 56) ? 1 : 0;
        int ow = pl - 56 * ohr;
        cellb[xf] = ohr * 58 + ow;
    }

    const int4v* wv = (const int4v*)wfr;

    int4v acc[4][7];
#pragma unroll
    for (int af = 0; af < 4; ++af)
#pragma unroll
        for (int xf = 0; xf < 7; ++xf) acc[af][xf] = {0, 0, 0, 0};

    int4v Af0[4], Bf0[7], Af1[4], Bf1[7];

#define LOAD_STEP(AF, BF, WQ, TAP, SLAB)                                      \
    {                                                                          \
        const int ab_ = (((WQ) * 9 + (TAP)) * 16 + wm * 4) * 64 + lane;        \
        _Pragma("unroll")                                                      \
        for (int af_ = 0; af_ < 4; ++af_) AF[af_] = wv[ab_ + af_ * 64];        \
        const int tsh_ = ((TAP) / 3) * 58 + ((TAP) % 3);                       \
        _Pragma("unroll")                                                      \
        for (int xf_ = 0; xf_ < 7; ++xf_) {                                    \
            int c_ = cellb[xf_] + tsh_;                                        \
            int by_ = c_ * 64 + (((kq ^ c_ ^ (c_ >> 2)) & 3) << 4);            \
            BF[xf_] = *(const int4v*)((SLAB) + by_);                           \
        }                                                                      \
    }

#define MMA_STEP(AF, BF)                                                       \
    {                                                                          \
        __builtin_amdgcn_s_setprio(1);                                         \
        _Pragma("unroll")                                                      \
        for (int xf_ = 0; xf_ < 7; ++xf_)                                      \
            _Pragma("unroll")                                                  \
            for (int af_ = 0; af_ < 4; ++af_)                                  \
                acc[af_][xf_] = __builtin_amdgcn_mfma_i32_16x16x64_i8(         \
                    AF[af_], BF[xf_], acc[af_][xf_], 0, 0, 0);                 \
        __builtin_amdgcn_s_setprio(0);                                         \
    }

    // ---- prologue: stage X slab q=0 ----
#pragma unroll
    for (int k = 0; k < 3; ++k)
        gload16(&Xl[0][(tid + k * 256) * 16], xpn + xgo[k]);
    if (tid < XCH - 768)
        gload16(&Xl[0][(tid + 768) * 16], xpn + xgo[3]);
    asm volatile("s_waitcnt vmcnt(0)" ::: "memory");
    __builtin_amdgcn_s_barrier();
    LOAD_STEP(Af0, Bf0, 0, 0, Xl[0]);

    for (int q = 0; q < 4; ++q) {
        const unsigned char* slab = Xl[q & 1];
        unsigned char* nslab = Xl[(q & 1) ^ 1];
        const bool qn = (q < 3);
#pragma unroll
        for (int s = 0; s < 9; ++s) {
            if (s < 8) {
                if (s & 1) { LOAD_STEP(Af0, Bf0, q, s + 1, slab); }
                else       { LOAD_STEP(Af1, Bf1, q, s + 1, slab); }
            }
            // drip-stage next q's slab at steps 2..5
            if (qn && s >= 2 && s <= 5) {
                const int k = s - 2;
                if (k < 3)
                    gload16(&nslab[(tid + k * 256) * 16], xpn + xgo[k] + (q + 1) * 64);
                else if (tid < XCH - 768)
                    gload16(&nslab[(tid + 768) * 16], xpn + xgo[3] + (q + 1) * 64);
            }
            __builtin_amdgcn_sched_barrier(0);
            if (s & 1) { MMA_STEP(Af1, Bf1); }
            else       { MMA_STEP(Af0, Bf0); }
        }
        if (qn) {
            asm volatile("s_waitcnt vmcnt(0)" ::: "memory");
            __builtin_amdgcn_s_barrier();
            if ((q & 1) == 0) { LOAD_STEP(Af0, Bf0, q + 1, 0, Xl[1]); }
            else              { LOAD_STEP(Af0, Bf0, q + 1, 0, Xl[0]); }
        }
    }

    // ---- epilogue: col = lane&15 -> pixel, row = kq*4+reg -> oc; dequant ----
    const float S = 5.0f / 127.0f;
    float* outn = out + (size_t)n * (OUT_C * HH * WW) + pix0;
#pragma unroll
    for (int xf = 0; xf < 7; ++xf) {
        float* op = outn + xf * 16 + rlo;
#pragma unroll
        for (int af = 0; af < 4; ++af) {
            int oc = wm * 64 + af * 16 + kq * 4;
#pragma unroll
            for (int r = 0; r < 4; ++r)
                op[(size_t)(oc + r) * (HH * WW)] = (float)acc[af][xf][r] * S;
        }
    }
}

extern "C" void kernel_launch(void* const* d_in, const int* in_sizes, int n_in,
                              void* d_out, int out_size, void* d_ws, size_t ws_size,
                              hipStream_t stream) {
    const float* x = (const float*)d_in[0];
    const float* wgt = (const float*)d_in[1];
    float* out = (float*)d_out;

    unsigned char* xpad = (unsigned char*)d_ws;                        // 27.6 MB
    size_t xpad_bytes = (size_t)NB * HP * WP * IN_C;
    unsigned char* wfr = (unsigned char*)((char*)d_ws + xpad_bytes);   // 0.59 MB

    hipLaunchKernelGGL(pad_nhwc, dim3(NB * HP), dim3(256), 0, stream, x, xpad);
    hipLaunchKernelGGL(wconv, dim3(144), dim3(256), 0, stream, wgt, wfr);
    hipLaunchKernelGGL(conv_i8, dim3(NTILE), dim3(256), 0, stream, xpad, wfr, out);
}

// Round 8
// 132.008 us; speedup vs baseline: 1.4067x; 1.4067x over previous
//
#include <hip/hip_runtime.h>
#include <stdint.h>

#define IN_C 256
#define OUT_C 256
#define HH 56
#define WW 56
#define NB 32
#define HP 58
#define WP 58

#define NTILE 1792       // 32 img * 28 row-pairs * 2 oc-halves = 8*224
#define XCH 1856         // slab chunks: 4 rows * 58 cols * 8
#define XSHORTS 14848    // 4*58*64 shorts = 29696 B

typedef __attribute__((ext_vector_type(8))) short short8;
typedef __attribute__((ext_vector_type(4))) float float4_t;

typedef const __attribute__((address_space(1))) unsigned int guint_t;
typedef __attribute__((address_space(3))) unsigned int luint_t;

__device__ __forceinline__ unsigned short f2bf(float f) {
    union { float f; unsigned u; } v; v.f = f;
    unsigned r = v.u + 0x7FFF + ((v.u >> 16) & 1);   // RNE
    return (unsigned short)(r >> 16);
}

__device__ __forceinline__ void gload16(void* lds, const void* g) {
    __builtin_amdgcn_global_load_lds((guint_t*)g, (luint_t*)lds, 16, 0, 0);
}

// ---------------- pre-pass 1: NCHW f32 -> padded NHWC bf16 ----------------
__global__ __launch_bounds__(256) void pad_nhwc(const float* __restrict__ x,
                                                unsigned short* __restrict__ xpad) {
    __shared__ float lds[WW * 257];
    int bid = blockIdx.x;
    int n = bid / HP, h = bid % HP;
    unsigned short* dstRow = xpad + (size_t)(n * HP + h) * WP * IN_C;
    bool hin = (h >= 1 && h <= HH);
    if (hin) {
        const float* src = x + (size_t)n * IN_C * (HH * WW) + (h - 1) * WW;
        for (int e = threadIdx.x; e < IN_C * WW; e += 256) {
            int ic = e / WW, w = e - ic * WW;
            lds[w * 257 + ic] = src[(size_t)ic * (HH * WW) + w];
        }
    }
    __syncthreads();
    for (int e = threadIdx.x; e < WP * (IN_C / 8); e += 256) {
        int wo = e / (IN_C / 8);
        int icc = e - wo * (IN_C / 8);
        short8 v = {0, 0, 0, 0, 0, 0, 0, 0};
        if (hin && wo >= 1 && wo <= WW) {
            const float* p = &lds[(wo - 1) * 257 + icc * 8];
#pragma unroll
            for (int j = 0; j < 8; ++j) v[j] = (short)f2bf(p[j]);
        }
        *(short8*)(dstRow + wo * IN_C + icc * 8) = v;
    }
}

// ---------- pre-pass 2: OIHW f32 -> A-frag-ready wfr, chunk i = [qt][s8][ks][af][lane] ----------
// i = qt*2048 + s8*256 + ks*128 + af*64 + lane  (chunks of 8 bf16)
// element: oc = s8*32 + af*16 + (lane&15), ic = q*64 + ks*32 + (lane>>4)*8 + j, tap = qt%9
__global__ __launch_bounds__(256) void wconv(const float* __restrict__ w,
                                             unsigned short* __restrict__ wfr) {
    int i = blockIdx.x * 256 + threadIdx.x;      // 73728 chunks
    int lane = i & 63;
    int af = (i >> 6) & 1;
    int ks = (i >> 7) & 1;
    int s8 = (i >> 8) & 7;
    int qt = i >> 11;                            // 0..35
    int tap = qt % 9;
    int q = qt / 9;
    int oc = s8 * 32 + af * 16 + (lane & 15);
    int icb = q * 64 + ks * 32 + (lane >> 4) * 8;
    unsigned short* dst = wfr + (size_t)i * 8;
#pragma unroll
    for (int j = 0; j < 8; ++j)
        dst[j] = f2bf(w[((size_t)oc * 256 + icb + j) * 9 + tap]);
}

// ---------------- main: 4-wave blocks (32oc x 112px per wave), 3 blocks/CU ----------------
__global__ __launch_bounds__(256, 3) void conv_mfma(const unsigned short* __restrict__ xpad,
                                                    const unsigned short* __restrict__ wfr,
                                                    float* __restrict__ out) {
    __shared__ unsigned short Xl[XSHORTS];   // 4 rows x 58 cols x 64 ic, chunk-swizzled

    const int tid = threadIdx.x;
    const int lane = tid & 63;
    const int wid = tid >> 6;                // 0..3 : 32-oc slice within the half

    const int bid = blockIdx.x;
    const int xcd = bid & 7, loc = bid >> 3;         // 4 images per XCD
    const int n = xcd * 4 + loc / 56;
    const int r = loc % 56;
    const int h = r & 1;                     // oc half (0/1); halves of same px-tile adjacent
    const int rg = r >> 1;
    const int oh0 = rg * 2;                  // padded rows oh0..oh0+3
    const int pix0 = rg * 112;

    const unsigned short* xpn = xpad + (size_t)n * HP * WP * IN_C;

    // ---- X staging addressing (8 chunks/thread), rule #21 swizzle ----
    int xgo[8];
#pragma unroll
    for (int k = 0; k < 8; ++k) {
        int ci = tid + k * 256; if (ci > XCH - 1) ci = XCH - 1;
        int rc = ci >> 3, pc = ci & 7;
        int row = rc / 58, col = rc - row * 58;
        xgo[k] = ((oh0 + row) * WP + col) * IN_C + (pc ^ (col & 7)) * 8;
    }

    // ---- B-frag addressing ----
    const int rlo = lane & 15;
    const int kq = lane >> 4;
    int rcb[7], owl[7];
#pragma unroll
    for (int xf = 0; xf < 7; ++xf) {
        int pl = xf * 16 + rlo;              // 0..111
        int ohr = (pl >= 56) ? 1 : 0;
        int ow = pl - 56 * ohr;
        rcb[xf] = (ohr * 58 + ow) * 128;     // byte offset of cell
        owl[xf] = ow & 7;
    }

    // ---- A-frag base: chunks [qt][s8][ks][af][lane], s8 = h*4+wid ----
    const unsigned short* wbase = wfr + (size_t)((h * 4 + wid) * 256 + lane) * 8;

    float4_t acc[2][7];
#pragma unroll
    for (int af = 0; af < 2; ++af)
#pragma unroll
        for (int xf = 0; xf < 7; ++xf) acc[af][xf] = {0.f, 0.f, 0.f, 0.f};

    short8 A0[2], A1[2], Bf[7];

#define LOAD_A(AF, QT, KS)                                                        \
    {                                                                              \
        const unsigned short* p_ = wbase + (size_t)((QT)*2048 + (KS)*128) * 8;     \
        AF[0] = *(const short8*)p_;                                                \
        AF[1] = *(const short8*)(p_ + 512);                                        \
    }

#define READ_B(TAP, KS)                                                           \
    {                                                                              \
        const int tsh_ = (((TAP) / 3) * 58 + ((TAP) % 3)) * 128;                   \
        _Pragma("unroll")                                                          \
        for (int xf_ = 0; xf_ < 7; ++xf_) {                                        \
            int ch_ = ((kq + (KS)*4) ^ ((owl[xf_] + ((TAP) % 3)) & 7)) * 16;       \
            Bf[xf_] = *(const short8*)((const char*)Xl + rcb[xf_] + tsh_ + ch_);   \
        }                                                                          \
    }

#define MMA(AF)                                                                   \
    {                                                                              \
        __builtin_amdgcn_s_setprio(1);                                             \
        _Pragma("unroll")                                                          \
        for (int xf_ = 0; xf_ < 7; ++xf_)                                          \
            _Pragma("unroll")                                                      \
            for (int af_ = 0; af_ < 2; ++af_)                                      \
                acc[af_][xf_] = __builtin_amdgcn_mfma_f32_16x16x32_bf16(           \
                    AF[af_], Bf[xf_], acc[af_][xf_], 0, 0, 0);                     \
        __builtin_amdgcn_s_setprio(0);                                             \
    }

    LOAD_A(A0, 0, 0);   // q=0, tap=0, ks=0

    for (int q = 0; q < 4; ++q) {
        // ---- stage X slab for this q (single-buffered; TLP covers the drain) ----
        if (q) __builtin_amdgcn_s_barrier();          // all waves done reading prev slab
#pragma unroll
        for (int k = 0; k < 7; ++k)
            gload16(&Xl[(tid + k * 256) * 8], xpn + xgo[k] + q * 64);
        if (tid < XCH - 1792)
            gload16(&Xl[(tid + 1792) * 8], xpn + xgo[7] + q * 64);
        asm volatile("s_waitcnt vmcnt(0)" ::: "memory");
        __builtin_amdgcn_s_barrier();
        __builtin_amdgcn_sched_barrier(0);

        const int qt0 = q * 9;
#pragma unroll
        for (int s = 0; s < 18; ++s) {
            const int tap = s >> 1, ks = s & 1;
            // prefetch next step's A-frags into the other set
            if (s < 17) {
                if (s & 1) { LOAD_A(A0, qt0 + ((s + 1) >> 1), (s + 1) & 1); }
                else       { LOAD_A(A1, qt0 + ((s + 1) >> 1), (s + 1) & 1); }
            } else if (q < 3) {
                LOAD_A(A0, qt0 + 9, 0);               // first step of next q (even parity)
            }
            READ_B(tap, ks);
            __builtin_amdgcn_sched_barrier(0);
            if (s & 1) { MMA(A1); }
            else       { MMA(A0); }
        }
    }

    // ---- epilogue: col = lane&15 -> pixel, row = kq*4+reg -> oc; xf innermost ----
    float* outn = out + (size_t)n * (OUT_C * HH * WW) + pix0 + rlo;
    const int ocb = h * 128 + wid * 32 + kq * 4;
#pragma unroll
    for (int af = 0; af < 2; ++af)
#pragma unroll
        for (int rr = 0; rr < 4; ++rr) {
            float* op = outn + (size_t)(ocb + af * 16 + rr) * (HH * WW);
#pragma unroll
            for (int xf = 0; xf < 7; ++xf)
                op[xf * 16] = acc[af][xf][rr];
        }
}

extern "C" void kernel_launch(void* const* d_in, const int* in_sizes, int n_in,
                              void* d_out, int out_size, void* d_ws, size_t ws_size,
                              hipStream_t stream) {
    const float* x = (const float*)d_in[0];
    const float* wgt = (const float*)d_in[1];
    float* out = (float*)d_out;

    unsigned short* xpad = (unsigned short*)d_ws;                       // 55.1 MB
    size_t xpad_bytes = (size_t)NB * HP * WP * IN_C * 2;
    unsigned short* wfr = (unsigned short*)((char*)d_ws + xpad_bytes);  // 1.18 MB

    hipLaunchKernelGGL(pad_nhwc, dim3(NB * HP), dim3(256), 0, stream, x, xpad);
    hipLaunchKernelGGL(wconv, dim3(288), dim3(256), 0, stream, wgt, wfr);
    hipLaunchKernelGGL(conv_mfma, dim3(NTILE), dim3(256), 0, stream, xpad, wfr, out);
}